// Round 6
// baseline (426.679 us; speedup 1.0000x reference)
//
#include <hip/hip_runtime.h>
#include <stdint.h>

// ResNetLinLnDrop: out = swish(LN2(swish(LN1(x)·W1^T))·W2^T) + x
// B=8,S=8192,D=768,H=384 -> M=65536 rows.
//
// LN folded past GEMM:  h = rs*(h0 - mu*Gw[n]) + Cb[n],  h0 = x·(W∘g)^T
//
// R6 (from R5 counters: traffic ideal [FETCH 217 / WRITE 197 MB] but all
//     pipes idle [Mfma 8%, VALU 17%, hbm 13%] -> latency-bound; GEMM1's
//     12 __syncthreads each drain vmcnt(0) incl. the ~900cyc HBM x loads):
//  - GEMM1 LDS staging REMOVED. All 4 waves need the same 32 rows, so each
//    lane loads its A-fragment directly from x (16 contig f32 = 64B/lane,
//    coalesced; 4x wave redundancy is L1/L2-absorbed) + converts to bf16.
//  - LN1 stats fully in-register per wave (shfl_xor 16/32 + shfl bcast):
//    no stats LDS, no barrier.
//  - barriers per block: 14 -> 2 (only the ldsS / LN2 cross-wave handoff).
//    GEMM1 + GEMM2 are barrier-free VMEM+MFMA streams.

typedef float  f32x4  __attribute__((ext_vector_type(4)));
typedef short  bf16x8 __attribute__((ext_vector_type(8)));

#define D1 768
#define H1 384

__device__ __forceinline__ unsigned short f32_to_bf16(float f) {
    union { float f; unsigned int u; } v; v.f = f;
    unsigned int u = v.u;
    return (unsigned short)((u + 0x7FFFu + ((u >> 16) & 1u)) >> 16); // RNE
}

__device__ __forceinline__ bf16x8 pack8(const float4& a, const float4& b) {
    union { bf16x8 v; unsigned short s[8]; } u;
    u.s[0] = f32_to_bf16(a.x); u.s[1] = f32_to_bf16(a.y);
    u.s[2] = f32_to_bf16(a.z); u.s[3] = f32_to_bf16(a.w);
    u.s[4] = f32_to_bf16(b.x); u.s[5] = f32_to_bf16(b.y);
    u.s[6] = f32_to_bf16(b.z); u.s[7] = f32_to_bf16(b.w);
    return u.v;
}

// ---------------- prep: fold gamma into weights, per-col LN constants --------
__global__ void prep_kernel(const float* __restrict__ W1, const float* __restrict__ W2,
                            const float* __restrict__ g1, const float* __restrict__ b1,
                            const float* __restrict__ g2, const float* __restrict__ b2,
                            unsigned short* __restrict__ W1g, unsigned short* __restrict__ W2g,
                            float* __restrict__ Gw1, float* __restrict__ Cb1,
                            float* __restrict__ Gw2, float* __restrict__ Cb2) {
    int wid  = (blockIdx.x * blockDim.x + threadIdx.x) >> 6;
    int lane = threadIdx.x & 63;
    if (wid < H1) {                    // W1 row: n over H1, k over D1
        int r = wid;
        float sg = 0.f, sb = 0.f;
        for (int c = lane; c < D1; c += 64) {
            float w = W1[r * D1 + c];
            float g = g1[c], b = b1[c];
            sg += g * w; sb += b * w;
            W1g[r * D1 + c] = f32_to_bf16(w * g);
        }
        for (int off = 32; off; off >>= 1) { sg += __shfl_xor(sg, off); sb += __shfl_xor(sb, off); }
        if (lane == 0) { Gw1[r] = sg; Cb1[r] = sb; }
    } else if (wid < H1 + D1) {        // W2 row: n over D1, k over H1
        int r = wid - H1;
        float sg = 0.f, sb = 0.f;
        for (int c = lane; c < H1; c += 64) {
            float w = W2[r * H1 + c];
            float g = g2[c], b = b2[c];
            sg += g * w; sb += b * w;
            W2g[r * H1 + c] = f32_to_bf16(w * g);
        }
        for (int off = 32; off; off >>= 1) { sg += __shfl_xor(sg, off); sb += __shfl_xor(sb, off); }
        if (lane == 0) { Gw2[r] = sg; Cb2[r] = sb; }
    }
}

// ---------------- fused main kernel -----------------------------------------
__global__ __launch_bounds__(256, 3) void fused_kernel(
    const float* __restrict__ x,
    const unsigned short* __restrict__ W1g, const unsigned short* __restrict__ W2g,
    const float* __restrict__ Gw1, const float* __restrict__ Cb1,
    const float* __restrict__ Gw2, const float* __restrict__ Cb2,
    float* __restrict__ out)
{
    __shared__ __align__(16) unsigned short ldsS[32 * 384];    // 24KB swish output s (bf16, swizzled)
    __shared__ float red[4][32][2];                            // 1KB  cross-wave LN2 partials
    __shared__ float stats2[32][2];                            // mu2, rs2 per row

    const int tid  = threadIdx.x;
    const int wave = tid >> 6;         // 0..3
    const int lane = tid & 63;
    const int l15  = lane & 15;
    const int l4   = lane >> 4;
    const int row0 = blockIdx.x * 32;
    const int nb   = wave * 96;        // wave's n-slice (96 of 384)

    f32x4 acc[2][6];
    #pragma unroll
    for (int m = 0; m < 2; ++m)
        #pragma unroll
        for (int n = 0; n < 6; ++n) acc[m][n] = f32x4{0.f, 0.f, 0.f, 0.f};

    float sum[2] = {0.f, 0.f}, sq[2] = {0.f, 0.f};

    // per-lane B base: W1g[n = nb+l15][k = l4*8]
    const unsigned short* w1p = W1g + (size_t)(nb + l15) * D1 + l4 * 8;
    // per-lane A base: x[row = row0+l15][k = l4*8]  (mt adds 16 rows)
    const float* xA = x + (size_t)(row0 + l15) * D1 + l4 * 8;

    // ======= GEMM1: h0 = bf16(x)·W1g^T, K=768, direct A loads, NO barriers ===
    for (int kc = 0; kc < 12; ++kc) {
        bf16x8 afr[2][2];
        #pragma unroll
        for (int mt = 0; mt < 2; ++mt) {
            const float* p = xA + mt * 16 * D1 + kc * 64;
            float4 u0 = *(const float4*)(p + 0);       // ks=0: k = kc*64 + l4*8
            float4 u1 = *(const float4*)(p + 4);
            float4 u2 = *(const float4*)(p + 32);      // ks=1: k = kc*64+32 + l4*8
            float4 u3 = *(const float4*)(p + 36);
            sum[mt] += (u0.x+u0.y+u0.z+u0.w) + (u1.x+u1.y+u1.z+u1.w)
                     + (u2.x+u2.y+u2.z+u2.w) + (u3.x+u3.y+u3.z+u3.w);
            sq[mt]  += u0.x*u0.x+u0.y*u0.y+u0.z*u0.z+u0.w*u0.w
                     + u1.x*u1.x+u1.y*u1.y+u1.z*u1.z+u1.w*u1.w
                     + u2.x*u2.x+u2.y*u2.y+u2.z*u2.z+u2.w*u2.w
                     + u3.x*u3.x+u3.y*u3.y+u3.z*u3.z+u3.w*u3.w;
            afr[mt][0] = pack8(u0, u1);
            afr[mt][1] = pack8(u2, u3);
        }
        #pragma unroll
        for (int ks = 0; ks < 2; ++ks) {
            bf16x8 bfr[6];
            #pragma unroll
            for (int nt = 0; nt < 6; ++nt)
                bfr[nt] = *(const bf16x8*)(w1p + nt * 16 * D1 + kc * 64 + ks * 32);
            #pragma unroll
            for (int mt = 0; mt < 2; ++mt)
                #pragma unroll
                for (int nt = 0; nt < 6; ++nt)
                    acc[mt][nt] = __builtin_amdgcn_mfma_f32_16x16x32_bf16(
                        afr[mt][ks], bfr[nt], acc[mt][nt], 0, 0, 0);
        }
    }

    // ---- LN1 stats fully in-register: every wave saw all 768 k of each row.
    // After xor-16/32 reduce, every lane holds row totals for rows l15 (mt0)
    // and 16+l15 (mt1).
    #pragma unroll
    for (int mt = 0; mt < 2; ++mt) {
        sum[mt] += __shfl_xor(sum[mt], 16); sum[mt] += __shfl_xor(sum[mt], 32);
        sq[mt]  += __shfl_xor(sq[mt],  16); sq[mt]  += __shfl_xor(sq[mt],  32);
    }

    float gw1[6], cb1[6];
    #pragma unroll
    for (int nt = 0; nt < 6; ++nt) {
        int c = nb + nt * 16 + l15;
        gw1[nt] = Gw1[c]; cb1[nt] = Cb1[c];
    }

    // ---- epilogue1: LN1 fix-up, swish, s->ldsS (bf16), LN2 partial stats ----
    #pragma unroll
    for (int mt = 0; mt < 2; ++mt) {
        #pragma unroll
        for (int reg = 0; reg < 4; ++reg) {
            int lrow = mt * 16 + l4 * 4 + reg;
            // broadcast row (l4*4+reg)'s totals from the lane holding them
            float mu = __shfl(sum[mt], l4 * 4 + reg) * (1.f / 768.f);
            float m2 = __shfl(sq[mt],  l4 * 4 + reg) * (1.f / 768.f);
            float rs = rsqrtf(m2 - mu * mu + 1e-5f);
            float psum = 0.f, psq = 0.f;
            #pragma unroll
            for (int nt = 0; nt < 6; ++nt) {
                float h0 = acc[mt][nt][reg];
                float h  = rs * (h0 - mu * gw1[nt]) + cb1[nt];
                float s  = h / (1.f + __expf(-h));
                psum += s; psq += s * s;
                int col = nb + nt * 16 + l15;
                int byt = lrow * 768 + col * 2;
                *(unsigned short*)((char*)ldsS + (byt ^ ((lrow & 7) << 4))) = f32_to_bf16(s);
            }
            psum += __shfl_xor(psum, 1); psum += __shfl_xor(psum, 2);
            psum += __shfl_xor(psum, 4); psum += __shfl_xor(psum, 8);
            psq  += __shfl_xor(psq,  1); psq  += __shfl_xor(psq,  2);
            psq  += __shfl_xor(psq,  4); psq  += __shfl_xor(psq,  8);
            if (l15 == 0) { red[wave][lrow][0] = psum;
                            red[wave][lrow][1] = psq; }
        }
    }
    __syncthreads();                                   // barrier 1 of 2
    if (tid < 32) {
        float s0 = 0.f, q0 = 0.f;
        #pragma unroll
        for (int w = 0; w < 4; ++w) { s0 += red[w][tid][0]; q0 += red[w][tid][1]; }
        float mu  = s0 * (1.f / 384.f);
        float var = q0 * (1.f / 384.f) - mu * mu;
        stats2[tid][0] = mu;
        stats2[tid][1] = rsqrtf(var + 1e-5f);
    }
    __syncthreads();                                   // barrier 2 of 2

    // ================= GEMM2: y0 = s · W2g^T, K=384, N=768 in two passes =====
    #pragma unroll
    for (int p = 0; p < 2; ++p) {
        #pragma unroll
        for (int m = 0; m < 2; ++m)
            #pragma unroll
            for (int n = 0; n < 6; ++n) acc[m][n] = f32x4{0.f, 0.f, 0.f, 0.f};

        const int ncb = p * 384 + nb;
        const unsigned short* w2p = W2g + (size_t)(ncb + l15) * H1 + l4 * 8;

        #pragma unroll
        for (int ks2 = 0; ks2 < 12; ++ks2) {
            bf16x8 bcur[6];
            #pragma unroll
            for (int nt = 0; nt < 6; ++nt)
                bcur[nt] = *(const bf16x8*)(w2p + nt * 16 * H1 + ks2 * 32);
            bf16x8 afr[2];
            #pragma unroll
            for (int mt = 0; mt < 2; ++mt) {
                int row = mt * 16 + l15;
                int off = (row * 768 + ks2 * 64 + l4 * 16) ^ ((row & 7) << 4);
                afr[mt] = *(const bf16x8*)((const char*)ldsS + off);
            }
            #pragma unroll
            for (int mt = 0; mt < 2; ++mt)
                #pragma unroll
                for (int nt = 0; nt < 6; ++nt)
                    acc[mt][nt] = __builtin_amdgcn_mfma_f32_16x16x32_bf16(
                        afr[mt], bcur[nt], acc[mt][nt], 0, 0, 0);
        }

        float gw2[6], cb2[6];
        #pragma unroll
        for (int nt = 0; nt < 6; ++nt) {
            int c = ncb + nt * 16 + l15;
            gw2[nt] = Gw2[c]; cb2[nt] = Cb2[c];
        }
        #pragma unroll
        for (int mt = 0; mt < 2; ++mt) {
            #pragma unroll
            for (int reg = 0; reg < 4; ++reg) {
                int lrow = mt * 16 + l4 * 4 + reg;
                float mu2 = stats2[lrow][0], rs2 = stats2[lrow][1];
                #pragma unroll
                for (int nt = 0; nt < 6; ++nt) {
                    int col = ncb + nt * 16 + l15;
                    float y0 = acc[mt][nt][reg];
                    float y  = rs2 * (y0 - mu2 * gw2[nt]) + cb2[nt];
                    float o  = y / (1.f + __expf(-y));
                    size_t gi = (size_t)(row0 + lrow) * D1 + col;
                    out[gi] = o + x[gi];
                }
            }
        }
    }
}

// ---------------- host launch ------------------------------------------------
extern "C" void kernel_launch(void* const* d_in, const int* in_sizes, int n_in,
                              void* d_out, int out_size, void* d_ws, size_t ws_size,
                              hipStream_t stream) {
    const float* x  = (const float*)d_in[0];
    const float* W1 = (const float*)d_in[1];
    const float* W2 = (const float*)d_in[2];
    const float* g1 = (const float*)d_in[3];
    const float* b1 = (const float*)d_in[4];
    const float* g2 = (const float*)d_in[5];
    const float* b2 = (const float*)d_in[6];
    float* out = (float*)d_out;

    char* ws = (char*)d_ws;
    unsigned short* W1g = (unsigned short*)(ws + 0);        // 384*768*2 = 589824
    unsigned short* W2g = (unsigned short*)(ws + 589824);   // 768*384*2 = 589824
    float* Gw1 = (float*)(ws + 1179648);                    // 384*4
    float* Cb1 = (float*)(ws + 1181184);                    // 384*4
    float* Gw2 = (float*)(ws + 1182720);                    // 768*4
    float* Cb2 = (float*)(ws + 1185792);                    // 768*4

    prep_kernel<<<288, 256, 0, stream>>>(W1, W2, g1, b1, g2, b2,
                                         W1g, W2g, Gw1, Cb1, Gw2, Cb2);
    fused_kernel<<<2048, 256, 0, stream>>>(x, W1g, W2g, Gw1, Cb1, Gw2, Cb2, out);
}

// Round 7
// 345.529 us; speedup vs baseline: 1.2349x; 1.2349x over previous
//
#include <hip/hip_runtime.h>
#include <stdint.h>

// ResNetLinLnDrop: out = swish(LN2(swish(LN1(x)·W1^T))·W2^T) + x
// B=8,S=8192,D=768,H=384 -> M=65536 rows.
//
// LN folded past GEMM:  h = rs*(h0 - mu*Gw[n]) + Cb[n],  h0 = x·(W∘g)^T
//
// R7 (model from R1-R6: time ~ 1/(resident waves); latency-bound, nothing
//     throughput-bound; occupancy reg-limited at 132/wave):
//  - 512-thr 8-wave blocks, 32 rows, wave tile 32x48 -> acc[2][3]=24 AGPR,
//    ~90 regs/wave -> 2 blocks/CU at (512,4) = 16 waves/CU, no spill.
//  - ONE-SHOT A staging: whole 32x768 panel -> 48KB LDS bf16 in one
//    12-float4/thread burst (max MLP); LN1 stats folded in; GEMM1 then
//    barrier-free fully-unrolled K=768 (no per-chunk vmcnt(0) drains).
//  - residual read from staged bf16 panel (no 2nd global x read).
//  - GEMM2: two 48-col passes, acc stays 24. 3 barriers/block total.

typedef float  f32x4  __attribute__((ext_vector_type(4)));
typedef short  bf16x8 __attribute__((ext_vector_type(8)));

#define D1 768
#define H1 384

__device__ __forceinline__ unsigned short f32_to_bf16(float f) {
    union { float f; unsigned int u; } v; v.f = f;
    unsigned int u = v.u;
    return (unsigned short)((u + 0x7FFFu + ((u >> 16) & 1u)) >> 16); // RNE
}

__device__ __forceinline__ float bf16_to_f32(unsigned short s) {
    union { unsigned int u; float f; } v; v.u = ((unsigned int)s) << 16;
    return v.f;
}

__device__ __forceinline__ bf16x8 pack8(const float4& a, const float4& b) {
    union { bf16x8 v; unsigned short s[8]; } u;
    u.s[0] = f32_to_bf16(a.x); u.s[1] = f32_to_bf16(a.y);
    u.s[2] = f32_to_bf16(a.z); u.s[3] = f32_to_bf16(a.w);
    u.s[4] = f32_to_bf16(b.x); u.s[5] = f32_to_bf16(b.y);
    u.s[6] = f32_to_bf16(b.z); u.s[7] = f32_to_bf16(b.w);
    return u.v;
}

// ---------------- prep: fold gamma into weights, per-col LN constants --------
__global__ void prep_kernel(const float* __restrict__ W1, const float* __restrict__ W2,
                            const float* __restrict__ g1, const float* __restrict__ b1,
                            const float* __restrict__ g2, const float* __restrict__ b2,
                            unsigned short* __restrict__ W1g, unsigned short* __restrict__ W2g,
                            float* __restrict__ Gw1, float* __restrict__ Cb1,
                            float* __restrict__ Gw2, float* __restrict__ Cb2) {
    int wid  = (blockIdx.x * blockDim.x + threadIdx.x) >> 6;
    int lane = threadIdx.x & 63;
    if (wid < H1) {                    // W1 row: n over H1, k over D1
        int r = wid;
        float sg = 0.f, sb = 0.f;
        for (int c = lane; c < D1; c += 64) {
            float w = W1[r * D1 + c];
            float g = g1[c], b = b1[c];
            sg += g * w; sb += b * w;
            W1g[r * D1 + c] = f32_to_bf16(w * g);
        }
        for (int off = 32; off; off >>= 1) { sg += __shfl_xor(sg, off); sb += __shfl_xor(sb, off); }
        if (lane == 0) { Gw1[r] = sg; Cb1[r] = sb; }
    } else if (wid < H1 + D1) {        // W2 row: n over D1, k over H1
        int r = wid - H1;
        float sg = 0.f, sb = 0.f;
        for (int c = lane; c < H1; c += 64) {
            float w = W2[r * H1 + c];
            float g = g2[c], b = b2[c];
            sg += g * w; sb += b * w;
            W2g[r * H1 + c] = f32_to_bf16(w * g);
        }
        for (int off = 32; off; off >>= 1) { sg += __shfl_xor(sg, off); sb += __shfl_xor(sb, off); }
        if (lane == 0) { Gw2[r] = sg; Cb2[r] = sb; }
    }
}

// ---------------- fused main kernel -----------------------------------------
__global__ __launch_bounds__(512, 4) void fused_kernel(
    const float* __restrict__ x,
    const unsigned short* __restrict__ W1g, const unsigned short* __restrict__ W2g,
    const float* __restrict__ Gw1, const float* __restrict__ Cb1,
    const float* __restrict__ Gw2, const float* __restrict__ Cb2,
    float* __restrict__ out)
{
    __shared__ __align__(16) unsigned short xA[32 * 768];   // 48KB whole x panel, bf16, swizzled
    __shared__ __align__(16) unsigned short ldsS[32 * 384]; // 24KB swish output s, bf16, swizzled
    __shared__ float red[8][32][2];                         // 2KB cross-wave LN2 partials
    __shared__ float stats1[32][2];                         // mu1, rs1 per row
    __shared__ float stats2[32][2];                         // mu2, rs2 per row

    const int tid  = threadIdx.x;
    const int wave = tid >> 6;         // 0..7
    const int lane = tid & 63;
    const int l15  = lane & 15;
    const int l4   = lane >> 4;
    const int row0 = blockIdx.x * 32;

    // ======= one-shot staging: x panel -> bf16 LDS + LN1 stats (1 barrier) ===
    {
        const int srow = tid >> 4;              // 0..31
        const int c0   = (tid & 15) * 48;       // 48 cols per thread
        const float* xp = x + (size_t)(row0 + srow) * D1 + c0;
        float4 v[12];
        #pragma unroll
        for (int j = 0; j < 12; ++j) v[j] = *(const float4*)(xp + 4 * j);
        float sum = 0.f, sq = 0.f;
        #pragma unroll
        for (int j = 0; j < 12; ++j) {
            sum += v[j].x + v[j].y + v[j].z + v[j].w;
            sq  += v[j].x*v[j].x + v[j].y*v[j].y + v[j].z*v[j].z + v[j].w*v[j].w;
        }
        const int swz = (srow & 7) << 4;
        const int rb  = srow * 1536 + c0 * 2;
        #pragma unroll
        for (int j = 0; j < 6; ++j)
            *(bf16x8*)((char*)xA + ((rb + 16 * j) ^ swz)) = pack8(v[2*j], v[2*j+1]);
        sum += __shfl_xor(sum, 1); sum += __shfl_xor(sum, 2);
        sum += __shfl_xor(sum, 4); sum += __shfl_xor(sum, 8);
        sq  += __shfl_xor(sq,  1); sq  += __shfl_xor(sq,  2);
        sq  += __shfl_xor(sq,  4); sq  += __shfl_xor(sq,  8);
        if ((tid & 15) == 0) {
            float mu = sum * (1.f / 768.f);
            float m2 = sq  * (1.f / 768.f);
            stats1[srow][0] = mu;
            stats1[srow][1] = rsqrtf(m2 - mu * mu + 1e-5f);
        }
    }
    __syncthreads();                                   // barrier 1 of 3

    // ======= GEMM1: h0 = bf16(x)·W1g^T, K=768, barrier-free, full unroll =====
    f32x4 acc[2][3];
    #pragma unroll
    for (int m = 0; m < 2; ++m)
        #pragma unroll
        for (int n = 0; n < 3; ++n) acc[m][n] = f32x4{0.f, 0.f, 0.f, 0.f};

    const int nb = wave * 48;          // wave's n-slice (48 of 384)
    const unsigned short* w1p = W1g + (size_t)(nb + l15) * D1 + l4 * 8;

    #pragma unroll
    for (int kc = 0; kc < 12; ++kc) {
        #pragma unroll
        for (int ks = 0; ks < 2; ++ks) {
            bf16x8 bfr[3];
            #pragma unroll
            for (int nt = 0; nt < 3; ++nt)
                bfr[nt] = *(const bf16x8*)(w1p + nt * 16 * D1 + kc * 64 + ks * 32);
            bf16x8 afr[2];
            #pragma unroll
            for (int mt = 0; mt < 2; ++mt) {
                int row = mt * 16 + l15;
                int off = (row * 1536 + kc * 128 + ks * 64 + l4 * 16) ^ ((row & 7) << 4);
                afr[mt] = *(const bf16x8*)((const char*)xA + off);
            }
            #pragma unroll
            for (int mt = 0; mt < 2; ++mt)
                #pragma unroll
                for (int nt = 0; nt < 3; ++nt)
                    acc[mt][nt] = __builtin_amdgcn_mfma_f32_16x16x32_bf16(
                        afr[mt], bfr[nt], acc[mt][nt], 0, 0, 0);
        }
    }

    // ---- epilogue1: LN1 fix-up, swish, s->ldsS (bf16), LN2 partial stats ----
    float gw1[3], cb1[3];
    #pragma unroll
    for (int nt = 0; nt < 3; ++nt) {
        int c = nb + nt * 16 + l15;
        gw1[nt] = Gw1[c]; cb1[nt] = Cb1[c];
    }
    #pragma unroll
    for (int mt = 0; mt < 2; ++mt) {
        #pragma unroll
        for (int reg = 0; reg < 4; ++reg) {
            int lrow = mt * 16 + l4 * 4 + reg;
            float mu = stats1[lrow][0], rs = stats1[lrow][1];
            float psum = 0.f, psq = 0.f;
            #pragma unroll
            for (int nt = 0; nt < 3; ++nt) {
                float h0 = acc[mt][nt][reg];
                float h  = rs * (h0 - mu * gw1[nt]) + cb1[nt];
                float s  = h / (1.f + __expf(-h));
                psum += s; psq += s * s;
                int col = nb + nt * 16 + l15;
                int byt = lrow * 768 + col * 2;
                *(unsigned short*)((char*)ldsS + (byt ^ ((lrow & 7) << 4))) = f32_to_bf16(s);
            }
            psum += __shfl_xor(psum, 1); psum += __shfl_xor(psum, 2);
            psum += __shfl_xor(psum, 4); psum += __shfl_xor(psum, 8);
            psq  += __shfl_xor(psq,  1); psq  += __shfl_xor(psq,  2);
            psq  += __shfl_xor(psq,  4); psq  += __shfl_xor(psq,  8);
            if (l15 == 0) { red[wave][lrow][0] = psum;
                            red[wave][lrow][1] = psq; }
        }
    }
    __syncthreads();                                   // barrier 2 of 3
    if (tid < 32) {
        float s0 = 0.f, q0 = 0.f;
        #pragma unroll
        for (int w = 0; w < 8; ++w) { s0 += red[w][tid][0]; q0 += red[w][tid][1]; }
        float mu  = s0 * (1.f / 384.f);
        float var = q0 * (1.f / 384.f) - mu * mu;
        stats2[tid][0] = mu;
        stats2[tid][1] = rsqrtf(var + 1e-5f);
    }
    __syncthreads();                                   // barrier 3 of 3

    // ======= GEMM2: y0 = s·W2g^T, K=384; two 48-col passes, barrier-free =====
    #pragma unroll
    for (int p = 0; p < 2; ++p) {
        #pragma unroll
        for (int m = 0; m < 2; ++m)
            #pragma unroll
            for (int n = 0; n < 3; ++n) acc[m][n] = f32x4{0.f, 0.f, 0.f, 0.f};

        const int ncb = wave * 96 + p * 48;
        const unsigned short* w2p = W2g + (size_t)(ncb + l15) * H1 + l4 * 8;

        #pragma unroll
        for (int ks2 = 0; ks2 < 12; ++ks2) {
            bf16x8 bcur[3];
            #pragma unroll
            for (int nt = 0; nt < 3; ++nt)
                bcur[nt] = *(const bf16x8*)(w2p + nt * 16 * H1 + ks2 * 32);
            bf16x8 afr[2];
            #pragma unroll
            for (int mt = 0; mt < 2; ++mt) {
                int row = mt * 16 + l15;
                int off = (row * 768 + ks2 * 64 + l4 * 16) ^ ((row & 7) << 4);
                afr[mt] = *(const bf16x8*)((const char*)ldsS + off);
            }
            #pragma unroll
            for (int mt = 0; mt < 2; ++mt)
                #pragma unroll
                for (int nt = 0; nt < 3; ++nt)
                    acc[mt][nt] = __builtin_amdgcn_mfma_f32_16x16x32_bf16(
                        afr[mt], bcur[nt], acc[mt][nt], 0, 0, 0);
        }

        float gw2[3], cb2[3];
        #pragma unroll
        for (int nt = 0; nt < 3; ++nt) {
            int c = ncb + nt * 16 + l15;
            gw2[nt] = Gw2[c]; cb2[nt] = Cb2[c];
        }
        #pragma unroll
        for (int mt = 0; mt < 2; ++mt) {
            #pragma unroll
            for (int reg = 0; reg < 4; ++reg) {
                int lrow = mt * 16 + l4 * 4 + reg;
                float mu2 = stats2[lrow][0], rs2 = stats2[lrow][1];
                #pragma unroll
                for (int nt = 0; nt < 3; ++nt) {
                    int col = ncb + nt * 16 + l15;
                    float y0 = acc[mt][nt][reg];
                    float y  = rs2 * (y0 - mu2 * gw2[nt]) + cb2[nt];
                    float o  = y / (1.f + __expf(-y));
                    // residual from the staged bf16 panel (no 2nd global x read)
                    int xoff = (lrow * 1536 + col * 2) ^ ((lrow & 7) << 4);
                    float xr = bf16_to_f32(*(const unsigned short*)((const char*)xA + xoff));
                    out[(row0 + lrow) * D1 + col] = o + xr;
                }
            }
        }
    }
}

// ---------------- host launch ------------------------------------------------
extern "C" void kernel_launch(void* const* d_in, const int* in_sizes, int n_in,
                              void* d_out, int out_size, void* d_ws, size_t ws_size,
                              hipStream_t stream) {
    const float* x  = (const float*)d_in[0];
    const float* W1 = (const float*)d_in[1];
    const float* W2 = (const float*)d_in[2];
    const float* g1 = (const float*)d_in[3];
    const float* b1 = (const float*)d_in[4];
    const float* g2 = (const float*)d_in[5];
    const float* b2 = (const float*)d_in[6];
    float* out = (float*)d_out;

    char* ws = (char*)d_ws;
    unsigned short* W1g = (unsigned short*)(ws + 0);        // 384*768*2 = 589824
    unsigned short* W2g = (unsigned short*)(ws + 589824);   // 768*384*2 = 589824
    float* Gw1 = (float*)(ws + 1179648);                    // 384*4
    float* Cb1 = (float*)(ws + 1181184);                    // 384*4
    float* Gw2 = (float*)(ws + 1182720);                    // 768*4
    float* Cb2 = (float*)(ws + 1185792);                    // 768*4

    prep_kernel<<<288, 256, 0, stream>>>(W1, W2, g1, b1, g2, b2,
                                         W1g, W2g, Gw1, Cb1, Gw2, Cb2);
    fused_kernel<<<2048, 512, 0, stream>>>(x, W1g, W2g, Gw1, Cb1, Gw2, Cb2, out);
}

// Round 8
// 341.116 us; speedup vs baseline: 1.2508x; 1.0129x over previous
//
#include <hip/hip_runtime.h>
#include <stdint.h>

// ResNetLinLnDrop: out = swish(LN2(swish(LN1(x)·W1^T))·W2^T) + x
// B=8,S=8192,D=768,H=384 -> M=65536 rows.
//
// LN folded past GEMM:  h = rs*(h0 - mu*Gw[n]) + Cb[n],  h0 = x·(W∘g)^T
//
// R8 = R2 (best measured: 297us, 16 waves/CU) + spill-free GEMM2.
//   Cross-round model: TLP is the only lever that moved dur (R2: 16 waves
//   -> 297us beats every 8-14-wave config even with 160MB spill traffic).
//   Per-wave ILP attempts (R1 deep regs, R6/R7 barrier removal) all lost:
//   at (x,4)-bounds arch VGPRs pin at 64 -> ~2 iters lookahead max.
//   R2's one pathology was GEMM2's bcur+bnxt=48-reg prefetch spill
//   (WRITE 356 vs ideal 197MB). Fix: per-iter bcur[3] only (~50 arch regs).
//   - 64-row blocks, 512 thr / 8 waves, wave tile 64x48 (acc[4][3]=48 AGPR,
//     8 distinct 48-col slices -> no duplicate B loads).
//   - GEMM1: dbuf 64-k chunks, loads issued before MFMAs (2-phase).
//   - 2 blocks/CU (LDS 69KB) x 8 waves = 16 waves/CU.

typedef float  f32x4  __attribute__((ext_vector_type(4)));
typedef short  bf16x8 __attribute__((ext_vector_type(8)));

#define D1 768
#define H1 384

__device__ __forceinline__ unsigned short f32_to_bf16(float f) {
    union { float f; unsigned int u; } v; v.f = f;
    unsigned int u = v.u;
    return (unsigned short)((u + 0x7FFFu + ((u >> 16) & 1u)) >> 16); // RNE
}

__device__ __forceinline__ bf16x8 pack8(const float4& a, const float4& b) {
    union { bf16x8 v; unsigned short s[8]; } u;
    u.s[0] = f32_to_bf16(a.x); u.s[1] = f32_to_bf16(a.y);
    u.s[2] = f32_to_bf16(a.z); u.s[3] = f32_to_bf16(a.w);
    u.s[4] = f32_to_bf16(b.x); u.s[5] = f32_to_bf16(b.y);
    u.s[6] = f32_to_bf16(b.z); u.s[7] = f32_to_bf16(b.w);
    return u.v;
}

// ---------------- prep: fold gamma into weights, per-col LN constants --------
__global__ void prep_kernel(const float* __restrict__ W1, const float* __restrict__ W2,
                            const float* __restrict__ g1, const float* __restrict__ b1,
                            const float* __restrict__ g2, const float* __restrict__ b2,
                            unsigned short* __restrict__ W1g, unsigned short* __restrict__ W2g,
                            float* __restrict__ Gw1, float* __restrict__ Cb1,
                            float* __restrict__ Gw2, float* __restrict__ Cb2) {
    int wid  = (blockIdx.x * blockDim.x + threadIdx.x) >> 6;
    int lane = threadIdx.x & 63;
    if (wid < H1) {                    // W1 row: n over H1, k over D1
        int r = wid;
        float sg = 0.f, sb = 0.f;
        for (int c = lane; c < D1; c += 64) {
            float w = W1[r * D1 + c];
            float g = g1[c], b = b1[c];
            sg += g * w; sb += b * w;
            W1g[r * D1 + c] = f32_to_bf16(w * g);
        }
        for (int off = 32; off; off >>= 1) { sg += __shfl_xor(sg, off); sb += __shfl_xor(sb, off); }
        if (lane == 0) { Gw1[r] = sg; Cb1[r] = sb; }
    } else if (wid < H1 + D1) {        // W2 row: n over D1, k over H1
        int r = wid - H1;
        float sg = 0.f, sb = 0.f;
        for (int c = lane; c < H1; c += 64) {
            float w = W2[r * H1 + c];
            float g = g2[c], b = b2[c];
            sg += g * w; sb += b * w;
            W2g[r * H1 + c] = f32_to_bf16(w * g);
        }
        for (int off = 32; off; off >>= 1) { sg += __shfl_xor(sg, off); sb += __shfl_xor(sb, off); }
        if (lane == 0) { Gw2[r] = sg; Cb2[r] = sb; }
    }
}

// ---------------- fused main kernel -----------------------------------------
__global__ __launch_bounds__(512, 4) void fused_kernel(
    const float* __restrict__ x,
    const unsigned short* __restrict__ W1g, const unsigned short* __restrict__ W2g,
    const float* __restrict__ Gw1, const float* __restrict__ Cb1,
    const float* __restrict__ Gw2, const float* __restrict__ Cb2,
    float* __restrict__ out)
{
    __shared__ __align__(16) unsigned short ldsA[2][64 * 64];  // 16KB dbuf x chunk (bf16, swizzled)
    __shared__ __align__(16) unsigned short ldsS[64 * 384];    // 48KB swish output s (bf16, swizzled)
    __shared__ float red[8][64][2];                            // 4KB  cross-wave LN2 partials
    __shared__ float stats1[64][2];                            // mu1, rs1 per row
    __shared__ float stats2[64][2];                            // mu2, rs2 per row

    const int tid  = threadIdx.x;
    const int wave = tid >> 6;         // 0..7
    const int lane = tid & 63;
    const int l15  = lane & 15;
    const int l4   = lane >> 4;
    const int row0 = blockIdx.x * 64;
    const int nb   = wave * 48;        // wave's n-slice (48 of 384)

    // staging map: thread covers 8 consecutive cols of one row per chunk
    const int srow = tid >> 3;         // 0..63
    const int scol = (tid & 7) * 8;    // 0,8,...,56
    const float* xrow = x + (size_t)(row0 + srow) * D1 + scol;
    const int wb = ((srow * 128 + scol * 2) ^ ((srow & 7) << 4)); // LDS write byte off

    f32x4 acc[4][3];
    #pragma unroll
    for (int m = 0; m < 4; ++m)
        #pragma unroll
        for (int n = 0; n < 3; ++n) acc[m][n] = f32x4{0.f, 0.f, 0.f, 0.f};

    float sum = 0.f, sumsq = 0.f;

    // per-lane B base: W1g[n = nb+l15][k = l4*8]
    const unsigned short* w1p = W1g + (size_t)(nb + l15) * D1 + l4 * 8;

    // ---- prologue: stage chunk 0 into buf0 ----
    {
        float4 v0 = *(const float4*)(xrow + 0);
        float4 v1 = *(const float4*)(xrow + 4);
        sum   += (v0.x + v0.y + v0.z + v0.w) + (v1.x + v1.y + v1.z + v1.w);
        sumsq += v0.x*v0.x + v0.y*v0.y + v0.z*v0.z + v0.w*v0.w
               + v1.x*v1.x + v1.y*v1.y + v1.z*v1.z + v1.w*v1.w;
        *(bf16x8*)((char*)ldsA[0] + wb) = pack8(v0, v1);
    }
    __syncthreads();

    // ================= GEMM1: h0 = bf16(x) · W1g^T, K=768, dbuf 64-chunks =====
    int cur = 0;
    for (int kc = 0; kc < D1; kc += 64) {
        const bool hasNext = (kc + 64) < D1;
        float4 nv0, nv1;
        if (hasNext) {                       // issue next-chunk loads early
            nv0 = *(const float4*)(xrow + kc + 64);
            nv1 = *(const float4*)(xrow + kc + 68);
        }
        const char* bufc = (const char*)ldsA[cur];
        #pragma unroll
        for (int ks = 0; ks < 2; ++ks) {
            bf16x8 bfr[3];
            #pragma unroll
            for (int nt = 0; nt < 3; ++nt)
                bfr[nt] = *(const bf16x8*)(w1p + nt * 16 * D1 + kc + ks * 32);
            bf16x8 afr[4];
            #pragma unroll
            for (int mt = 0; mt < 4; ++mt) {
                int row = mt * 16 + l15;
                int off = (row * 128 + ks * 64 + l4 * 16) ^ ((row & 7) << 4);
                afr[mt] = *(const bf16x8*)(bufc + off);
            }
            #pragma unroll
            for (int mt = 0; mt < 4; ++mt)
                #pragma unroll
                for (int nt = 0; nt < 3; ++nt)
                    acc[mt][nt] = __builtin_amdgcn_mfma_f32_16x16x32_bf16(
                        afr[mt], bfr[nt], acc[mt][nt], 0, 0, 0);
        }
        if (hasNext) {                       // pack+write while loads have landed
            sum   += (nv0.x + nv0.y + nv0.z + nv0.w) + (nv1.x + nv1.y + nv1.z + nv1.w);
            sumsq += nv0.x*nv0.x + nv0.y*nv0.y + nv0.z*nv0.z + nv0.w*nv0.w
                   + nv1.x*nv1.x + nv1.y*nv1.y + nv1.z*nv1.z + nv1.w*nv1.w;
            *(bf16x8*)((char*)ldsA[cur ^ 1] + wb) = pack8(nv0, nv1);
        }
        __syncthreads();
        cur ^= 1;
    }

    // ---- LN1 stats: 8 threads (tid&7) own row srow, same wave ----
    sum   += __shfl_xor(sum,   1); sum   += __shfl_xor(sum,   2); sum   += __shfl_xor(sum,   4);
    sumsq += __shfl_xor(sumsq, 1); sumsq += __shfl_xor(sumsq, 2); sumsq += __shfl_xor(sumsq, 4);
    if ((tid & 7) == 0) {
        float mu  = sum * (1.f / 768.f);
        float var = sumsq * (1.f / 768.f) - mu * mu;
        stats1[srow][0] = mu;
        stats1[srow][1] = rsqrtf(var + 1e-5f);
    }
    __syncthreads();

    float gw1[3], cb1[3];
    #pragma unroll
    for (int nt = 0; nt < 3; ++nt) {
        int c = nb + nt * 16 + l15;
        gw1[nt] = Gw1[c]; cb1[nt] = Cb1[c];
    }

    // ---- epilogue1: LN1 fix-up, swish, s->ldsS (bf16), LN2 partial stats ----
    #pragma unroll
    for (int mt = 0; mt < 4; ++mt) {
        #pragma unroll
        for (int reg = 0; reg < 4; ++reg) {
            int lrow = mt * 16 + l4 * 4 + reg;
            float mu = stats1[lrow][0], rs = stats1[lrow][1];
            float psum = 0.f, psq = 0.f;
            #pragma unroll
            for (int nt = 0; nt < 3; ++nt) {
                float h0 = acc[mt][nt][reg];
                float h  = rs * (h0 - mu * gw1[nt]) + cb1[nt];
                float s  = h / (1.f + __expf(-h));
                psum += s; psq += s * s;
                int col = nb + nt * 16 + l15;
                int byt = lrow * 768 + col * 2;
                *(unsigned short*)((char*)ldsS + (byt ^ ((lrow & 7) << 4))) = f32_to_bf16(s);
            }
            psum += __shfl_xor(psum, 1); psum += __shfl_xor(psum, 2);
            psum += __shfl_xor(psum, 4); psum += __shfl_xor(psum, 8);
            psq  += __shfl_xor(psq,  1); psq  += __shfl_xor(psq,  2);
            psq  += __shfl_xor(psq,  4); psq  += __shfl_xor(psq,  8);
            if (l15 == 0) { red[wave][lrow][0] = psum; red[wave][lrow][1] = psq; }
        }
    }
    __syncthreads();
    if (tid < 64) {
        float s0 = 0.f, q0 = 0.f;
        #pragma unroll
        for (int w = 0; w < 8; ++w) { s0 += red[w][tid][0]; q0 += red[w][tid][1]; }
        float mu  = s0 * (1.f / 384.f);
        float var = q0 * (1.f / 384.f) - mu * mu;
        stats2[tid][0] = mu;
        stats2[tid][1] = rsqrtf(var + 1e-5f);
    }
    __syncthreads();

    // ================= GEMM2: y0 = s · W2g^T, K=384, N=768 in two passes =====
    #pragma unroll
    for (int p = 0; p < 2; ++p) {
        #pragma unroll
        for (int m = 0; m < 4; ++m)
            #pragma unroll
            for (int n = 0; n < 3; ++n) acc[m][n] = f32x4{0.f, 0.f, 0.f, 0.f};

        const int ncb = p * 384 + nb;
        const unsigned short* w2p = W2g + (size_t)(ncb + l15) * H1 + l4 * 8;

        // spill-free: per-iter bcur[3] only (no bnxt), ~50 arch regs peak.
        #pragma unroll
        for (int ks2 = 0; ks2 < 12; ++ks2) {
            bf16x8 bcur[3];
            #pragma unroll
            for (int nt = 0; nt < 3; ++nt)
                bcur[nt] = *(const bf16x8*)(w2p + nt * 16 * H1 + ks2 * 32);
            bf16x8 afr[4];
            #pragma unroll
            for (int mt = 0; mt < 4; ++mt) {
                int row = mt * 16 + l15;
                int off = (row * 768 + ks2 * 64 + l4 * 16) ^ ((row & 7) << 4);
                afr[mt] = *(const bf16x8*)((const char*)ldsS + off);
            }
            #pragma unroll
            for (int mt = 0; mt < 4; ++mt)
                #pragma unroll
                for (int nt = 0; nt < 3; ++nt)
                    acc[mt][nt] = __builtin_amdgcn_mfma_f32_16x16x32_bf16(
                        afr[mt], bcur[nt], acc[mt][nt], 0, 0, 0);
        }

        float gw2[3], cb2[3];
        #pragma unroll
        for (int nt = 0; nt < 3; ++nt) {
            int c = ncb + nt * 16 + l15;
            gw2[nt] = Gw2[c]; cb2[nt] = Cb2[c];
        }
        #pragma unroll
        for (int mt = 0; mt < 4; ++mt) {
            #pragma unroll
            for (int reg = 0; reg < 4; ++reg) {
                int lrow = mt * 16 + l4 * 4 + reg;
                float mu2 = stats2[lrow][0], rs2 = stats2[lrow][1];
                #pragma unroll
                for (int nt = 0; nt < 3; ++nt) {
                    int col = ncb + nt * 16 + l15;
                    float y0 = acc[mt][nt][reg];
                    float y  = rs2 * (y0 - mu2 * gw2[nt]) + cb2[nt];
                    float o  = y / (1.f + __expf(-y));
                    size_t gi = (size_t)(row0 + lrow) * D1 + col;
                    out[gi] = o + x[gi];
                }
            }
        }
    }
}

// ---------------- host launch ------------------------------------------------
extern "C" void kernel_launch(void* const* d_in, const int* in_sizes, int n_in,
                              void* d_out, int out_size, void* d_ws, size_t ws_size,
                              hipStream_t stream) {
    const float* x  = (const float*)d_in[0];
    const float* W1 = (const float*)d_in[1];
    const float* W2 = (const float*)d_in[2];
    const float* g1 = (const float*)d_in[3];
    const float* b1 = (const float*)d_in[4];
    const float* g2 = (const float*)d_in[5];
    const float* b2 = (const float*)d_in[6];
    float* out = (float*)d_out;

    char* ws = (char*)d_ws;
    unsigned short* W1g = (unsigned short*)(ws + 0);        // 384*768*2 = 589824
    unsigned short* W2g = (unsigned short*)(ws + 589824);   // 768*384*2 = 589824
    float* Gw1 = (float*)(ws + 1179648);                    // 384*4
    float* Cb1 = (float*)(ws + 1181184);                    // 384*4
    float* Gw2 = (float*)(ws + 1182720);                    // 768*4
    float* Cb2 = (float*)(ws + 1185792);                    // 768*4

    prep_kernel<<<288, 256, 0, stream>>>(W1, W2, g1, b1, g2, b2,
                                         W1g, W2g, Gw1, Cb1, Gw2, Cb2);
    fused_kernel<<<1024, 512, 0, stream>>>(x, W1g, W2g, Gw1, Cb1, Gw2, Cb2, out);
}